// Round 1
// baseline (273.283 us; speedup 1.0000x reference)
//
#include <hip/hip_runtime.h>
#include <math.h>

#define VOCAB_SZ 100000
#define EMB 256
#define NS 256
#define BATCH_SZ 16384
#define ROWS 32   // batch rows per block; LDS tile = 32 KB -> up to 4-5 blocks/CU

// log(NS * logUniformProb(id)), with log(id+2)-log(id+1) == log1p(1/(id+1))
__device__ __forceinline__ float log_corr(int id) {
    const float INV_LOG_RANGE = 1.0f / 11.5129354649f;  // 1/ln(100001)
    float p = log1pf(1.0f / ((float)id + 1.0f)) * INV_LOG_RANGE;
    return logf((float)NS * p);
}

extern "C" __global__ void __launch_bounds__(256)
nce_fused(const float* __restrict__ embeddings,
          const float* __restrict__ nce_weights,
          const float* __restrict__ nce_biases,
          const int*   __restrict__ inputs,
          const int*   __restrict__ labels,
          const int*   __restrict__ sampled_ids,
          float* __restrict__ out_embed,
          float* __restrict__ out_cost)
{
    __shared__ float se[ROWS * EMB];   // 32 KB embed tile
    __shared__ float wpart[4];

    const int t    = threadIdx.x;
    const int lane = t & 63;
    const int wv   = t >> 6;
    const int b0   = blockIdx.x * ROWS;

    // ---- Phase A: gather 32 embedding rows -> LDS + global out (float4) ----
    #pragma unroll
    for (int i = 0; i < 8; ++i) {
        int r = i * 4 + wv;           // 4 rows per iteration (one per wave)
        int b = b0 + r;
        int idx = inputs[b];
        const float4 v = *(const float4*)(embeddings + (size_t)idx * EMB + lane * 4);
        ((float4*)se)[r * 64 + lane] = v;
        *(float4*)(out_embed + (size_t)b * EMB + lane * 4) = v;
    }
    __syncthreads();

    float myloss = 0.0f;

    // ---- Phase B: true logits; wave wv handles rows wv*8 .. wv*8+7 ----
    #pragma unroll
    for (int j = 0; j < 8; ++j) {
        int r = wv * 8 + j;
        int b = b0 + r;
        int lab = labels[b];          // wave-uniform
        float4 w4 = *(const float4*)(nce_weights + (size_t)lab * EMB + lane * 4);
        float4 e4 = ((const float4*)se)[r * 64 + lane];
        float p = e4.x * w4.x + e4.y * w4.y + e4.z * w4.z + e4.w * w4.w;
        #pragma unroll
        for (int o = 32; o > 0; o >>= 1) p += __shfl_down(p, o, 64);
        if (lane == 0) {
            float tl = p + nce_biases[lab] - log_corr(lab);
            // sigmoid xent with label=1: max(x,0) - x + log1p(exp(-|x|))
            myloss += fmaxf(tl, 0.0f) - tl + log1pf(expf(-fabsf(tl)));
        }
    }

    // ---- Phase C: sampled logits; thread t owns sampled column s=t ----
    int sid = sampled_ids[t];
    float sc = nce_biases[sid] - log_corr(sid);
    const float4* wrow = (const float4*)(nce_weights + (size_t)sid * EMB);

    float acc[ROWS];
    #pragma unroll
    for (int r = 0; r < ROWS; ++r) acc[r] = 0.0f;

    for (int kq = 0; kq < EMB / 4; ++kq) {
        float4 wk = wrow[kq];                       // per-thread row, L2-resident
        #pragma unroll
        for (int r = 0; r < ROWS; ++r) {
            float4 e4 = ((const float4*)se)[r * 64 + kq];  // LDS broadcast
            acc[r] = fmaf(e4.x, wk.x, acc[r]);
            acc[r] = fmaf(e4.y, wk.y, acc[r]);
            acc[r] = fmaf(e4.z, wk.z, acc[r]);
            acc[r] = fmaf(e4.w, wk.w, acc[r]);
        }
    }

    #pragma unroll
    for (int r = 0; r < ROWS; ++r) {
        float x = acc[r] + sc;
        // sigmoid xent with label=0: max(x,0) + log1p(exp(-|x|))
        myloss += fmaxf(x, 0.0f) + log1pf(expf(-fabsf(x)));
    }

    // ---- block reduce + one atomic per block ----
    #pragma unroll
    for (int o = 32; o > 0; o >>= 1) myloss += __shfl_down(myloss, o, 64);
    if (lane == 0) wpart[wv] = myloss;
    __syncthreads();
    if (t == 0) {
        float s = wpart[0] + wpart[1] + wpart[2] + wpart[3];
        atomicAdd(out_cost, s * (1.0f / (float)BATCH_SZ));
    }
}

extern "C" void kernel_launch(void* const* d_in, const int* in_sizes, int n_in,
                              void* d_out, int out_size, void* d_ws, size_t ws_size,
                              hipStream_t stream) {
    const float* embeddings  = (const float*)d_in[0];
    const float* nce_weights = (const float*)d_in[1];
    const float* nce_biases  = (const float*)d_in[2];
    const int*   inputs      = (const int*)d_in[3];
    const int*   labels      = (const int*)d_in[4];   // (BATCH,1) flat
    const int*   sampled_ids = (const int*)d_in[5];

    float* out      = (float*)d_out;
    float* out_cost = out + (size_t)BATCH_SZ * EMB;

    // d_out is poisoned 0xAA before every launch; zero the scalar slot first.
    hipMemsetAsync(out_cost, 0, sizeof(float), stream);

    nce_fused<<<BATCH_SZ / ROWS, 256, 0, stream>>>(
        embeddings, nce_weights, nce_biases, inputs, labels, sampled_ids,
        out, out_cost);
}

// Round 2
// 231.774 us; speedup vs baseline: 1.1791x; 1.1791x over previous
//
#include <hip/hip_runtime.h>
#include <math.h>

#define VOCAB_SZ 100000
#define EMB 256
#define NS 256
#define BATCH_SZ 16384
#define ROWS 32            // batch rows per block
#define LDA 264            // padded LDS row stride (bf16 elems): +8 breaks bank aliasing

typedef __attribute__((ext_vector_type(8))) __bf16 bf16x8;
typedef __attribute__((ext_vector_type(4))) float  f32x4;

// log(NS * logUniformProb(id))
__device__ __forceinline__ float log_corr(int id) {
    const float INV_LOG_RANGE = 1.0f / 11.5129354649f;  // 1/ln(100001)
    float p = log1pf(1.0f / ((float)id + 1.0f)) * INV_LOG_RANGE;
    return logf((float)NS * p);
}

// fp32 -> bf16 bits, round-to-nearest-even
__device__ __forceinline__ unsigned short f2bf(float x) {
    unsigned int u = __float_as_uint(x);
    u += 0x7FFFu + ((u >> 16) & 1u);
    return (unsigned short)(u >> 16);
}
__device__ __forceinline__ float bf2f(unsigned short b) {
    return __uint_as_float(((unsigned int)b) << 16);
}

// ---- prep: gather sampled weight rows -> bf16 B[256][256] in ws, plus sc[s] ----
extern "C" __global__ void __launch_bounds__(64)
nce_prep(const float* __restrict__ nce_weights,
         const float* __restrict__ nce_biases,
         const int*   __restrict__ sampled_ids,
         unsigned short* __restrict__ Bws,
         float* __restrict__ scws)
{
    const int s = blockIdx.x;      // sample 0..255
    const int l = threadIdx.x;     // 0..63
    const int sid = sampled_ids[s];
    const float4 v = *(const float4*)(nce_weights + (size_t)sid * EMB + l * 4);
    ushort4 o;
    o.x = f2bf(v.x); o.y = f2bf(v.y); o.z = f2bf(v.z); o.w = f2bf(v.w);
    *(ushort4*)(Bws + (size_t)s * EMB + l * 4) = o;
    if (l == 0) scws[s] = nce_biases[sid] - log_corr(sid);
}

// ---- main fused kernel ----
extern "C" __global__ void __launch_bounds__(256)
nce_main(const float* __restrict__ embeddings,
         const float* __restrict__ nce_weights,
         const float* __restrict__ nce_biases,
         const int*   __restrict__ inputs,
         const int*   __restrict__ labels,
         const unsigned short* __restrict__ Bws,
         const float* __restrict__ scws,
         float* __restrict__ out_embed,
         float* __restrict__ out_cost)
{
    __shared__ unsigned short A[ROWS * LDA];   // 16.5 KB bf16 embed tile
    __shared__ float sc_l[NS];
    __shared__ float wpart[4];

    const int t    = threadIdx.x;
    const int lane = t & 63;
    const int wv   = t >> 6;
    const int b0   = blockIdx.x * ROWS;

    sc_l[t] = scws[t];

    // Phase A: gather 32 embed rows -> fp32 out + bf16 LDS
    #pragma unroll
    for (int i = 0; i < 8; ++i) {
        int r = i * 4 + wv;
        int b = b0 + r;
        int idx = inputs[b];
        const float4 v = *(const float4*)(embeddings + (size_t)idx * EMB + lane * 4);
        *(float4*)(out_embed + (size_t)b * EMB + lane * 4) = v;
        ushort4 o;
        o.x = f2bf(v.x); o.y = f2bf(v.y); o.z = f2bf(v.z); o.w = f2bf(v.w);
        *(ushort4*)(A + r * LDA + lane * 4) = o;
    }
    __syncthreads();

    float myloss = 0.0f;

    // Phase B: true logits, wave wv handles rows wv*8..wv*8+7
    #pragma unroll
    for (int j = 0; j < 8; ++j) {
        int r = wv * 8 + j;
        int b = b0 + r;
        int lab = labels[b];                       // wave-uniform
        float4 w4 = *(const float4*)(nce_weights + (size_t)lab * EMB + lane * 4);
        ushort4 e = *(const ushort4*)(A + r * LDA + lane * 4);
        float p = bf2f(e.x) * w4.x + bf2f(e.y) * w4.y +
                  bf2f(e.z) * w4.z + bf2f(e.w) * w4.w;
        #pragma unroll
        for (int o = 32; o > 0; o >>= 1) p += __shfl_down(p, o, 64);
        if (lane == 0) {
            float tl = p + nce_biases[lab] - log_corr(lab);
            myloss += fmaxf(tl, 0.0f) - tl + log1pf(expf(-fabsf(tl)));
        }
    }

    // Phase C: MFMA. Wave wv owns rows mrow..mrow+15, samples nbase..nbase+127.
    const int mrow  = (wv & 1) * 16;
    const int nbase = (wv >> 1) * 128;
    const int l15   = lane & 15;
    const int lq    = lane >> 4;

    const unsigned short* Arow  = A + (mrow + l15) * LDA + lq * 8;
    const unsigned short* Bbase = Bws + (size_t)(nbase + l15) * EMB + lq * 8;

    f32x4 acc[8];
    #pragma unroll
    for (int tt = 0; tt < 8; ++tt) acc[tt] = (f32x4){0.f, 0.f, 0.f, 0.f};

    #pragma unroll
    for (int k0 = 0; k0 < EMB; k0 += 32) {
        bf16x8 af = *(const bf16x8*)(Arow + k0);            // ds_read_b128
        #pragma unroll
        for (int tt = 0; tt < 8; ++tt) {
            bf16x8 bf = *(const bf16x8*)(Bbase + tt * 16 * EMB + k0);  // L2-hit
            acc[tt] = __builtin_amdgcn_mfma_f32_16x16x32_bf16(af, bf, acc[tt], 0, 0, 0);
        }
    }

    // Epilogue: x[m][n] = acc + sc[n]; xent label=0
    #pragma unroll
    for (int tt = 0; tt < 8; ++tt) {
        float scv = sc_l[nbase + tt * 16 + l15];
        #pragma unroll
        for (int i = 0; i < 4; ++i) {
            float x = acc[tt][i] + scv;
            myloss += fmaxf(x, 0.0f) + log1pf(expf(-fabsf(x)));
        }
    }

    // block reduce + one atomic
    #pragma unroll
    for (int o = 32; o > 0; o >>= 1) myloss += __shfl_down(myloss, o, 64);
    if (lane == 0) wpart[wv] = myloss;
    __syncthreads();
    if (t == 0) {
        float s = wpart[0] + wpart[1] + wpart[2] + wpart[3];
        atomicAdd(out_cost, s * (1.0f / (float)BATCH_SZ));
    }
}

extern "C" void kernel_launch(void* const* d_in, const int* in_sizes, int n_in,
                              void* d_out, int out_size, void* d_ws, size_t ws_size,
                              hipStream_t stream) {
    const float* embeddings  = (const float*)d_in[0];
    const float* nce_weights = (const float*)d_in[1];
    const float* nce_biases  = (const float*)d_in[2];
    const int*   inputs      = (const int*)d_in[3];
    const int*   labels      = (const int*)d_in[4];
    const int*   sampled_ids = (const int*)d_in[5];

    float* out      = (float*)d_out;
    float* out_cost = out + (size_t)BATCH_SZ * EMB;

    unsigned short* Bws  = (unsigned short*)d_ws;                      // 128 KB
    float*          scws = (float*)((char*)d_ws + NS * EMB * sizeof(unsigned short));

    hipMemsetAsync(out_cost, 0, sizeof(float), stream);

    nce_prep<<<NS, 64, 0, stream>>>(nce_weights, nce_biases, sampled_ids, Bws, scws);

    nce_main<<<BATCH_SZ / ROWS, 256, 0, stream>>>(
        embeddings, nce_weights, nce_biases, inputs, labels,
        Bws, scws, out, out_cost);
}

// Round 3
// 217.578 us; speedup vs baseline: 1.2560x; 1.0652x over previous
//
#include <hip/hip_runtime.h>
#include <math.h>

#define EMB 256
#define NS 256
#define BATCH_SZ 16384
#define ROWS 16            // batch rows per block
#define LDA 264            // padded LDS row stride (bf16 elems)

typedef __attribute__((ext_vector_type(8))) __bf16 bf16x8;
typedef __attribute__((ext_vector_type(4))) float  f32x4;

// log(NS * logUniformProb(id))
__device__ __forceinline__ float log_corr(int id) {
    const float INV_LOG_RANGE = 1.0f / 11.5129354649f;  // 1/ln(100001)
    float p = log1pf(1.0f / ((float)id + 1.0f)) * INV_LOG_RANGE;
    return logf((float)NS * p);
}
__device__ __forceinline__ unsigned short f2bf(float x) {
    unsigned int u = __float_as_uint(x);
    u += 0x7FFFu + ((u >> 16) & 1u);
    return (unsigned short)(u >> 16);
}
__device__ __forceinline__ float bf2f(unsigned short b) {
    return __uint_as_float(((unsigned int)b) << 16);
}

// ---- prep: gather sampled weight rows into MFMA-fragment-swizzled bf16 B ----
// Bsw element (T, kb, lane, j) = W[s = T*16 + (lane&15)][k = kb*32 + (lane>>4)*8 + j]
// so a wave's B-fragment load for tile T, k-block kb is ONE contiguous 1-KB read.
extern "C" __global__ void __launch_bounds__(64)
nce_prep(const float* __restrict__ nce_weights,
         const float* __restrict__ nce_biases,
         const int*   __restrict__ sampled_ids,
         unsigned short* __restrict__ Bsw,
         float* __restrict__ scws,
         float* __restrict__ out_cost)
{
    const int tid = blockIdx.x * 64 + threadIdx.x;   // 0..8191
    const int s   = tid >> 5;                        // sample 0..255
    const int u   = tid & 31;                        // 8-elem k-chunk 0..31
    const int sid = sampled_ids[s];
    const float4* wr = (const float4*)(nce_weights + (size_t)sid * EMB + u * 8);
    float4 a = wr[0], b = wr[1];
    unsigned short o[8] = { f2bf(a.x), f2bf(a.y), f2bf(a.z), f2bf(a.w),
                            f2bf(b.x), f2bf(b.y), f2bf(b.z), f2bf(b.w) };
    const int T = s >> 4, kb = u >> 2;
    const int lane = ((u & 3) << 4) | (s & 15);
    unsigned short* dst = Bsw + ((size_t)((T * 8 + kb) * 64 + lane)) * 8;
    *(ushort4*)(dst)     = *(ushort4*)&o[0];
    *(ushort4*)(dst + 4) = *(ushort4*)&o[4];
    if (u == 0) scws[s] = nce_biases[sid] - log_corr(sid);
    if (tid == 0) *out_cost = 0.0f;    // main kernel runs after on same stream
}

// ---- main fused kernel: 1024 blocks x 256 thr, 16 batch rows/block ----
extern "C" __global__ void __launch_bounds__(256)
nce_main(const float* __restrict__ embeddings,
         const float* __restrict__ nce_weights,
         const float* __restrict__ nce_biases,
         const int*   __restrict__ inputs,
         const int*   __restrict__ labels,
         const unsigned short* __restrict__ Bsw,
         const float* __restrict__ scws,
         float* __restrict__ out_embed,
         float* __restrict__ out_cost)
{
    __shared__ unsigned short A[ROWS * LDA];   // 8.25 KB bf16 embed tile
    __shared__ float sc_l[NS];
    __shared__ float wpart[4];

    const int t    = threadIdx.x;
    const int lane = t & 63;
    const int wv   = t >> 6;
    const int b0   = blockIdx.x * ROWS;

    sc_l[t] = scws[t];

    // Phase A: gather 16 embed rows -> fp32 out + bf16 LDS (wave per row)
    #pragma unroll
    for (int i = 0; i < 4; ++i) {
        int r = i * 4 + wv;
        int b = b0 + r;
        int idx = inputs[b];
        const float4 v = *(const float4*)(embeddings + (size_t)idx * EMB + lane * 4);
        *(float4*)(out_embed + (size_t)b * EMB + lane * 4) = v;
        ushort4 o;
        o.x = f2bf(v.x); o.y = f2bf(v.y); o.z = f2bf(v.z); o.w = f2bf(v.w);
        *(ushort4*)(A + r * LDA + lane * 4) = o;
    }
    __syncthreads();

    float myloss = 0.0f;

    // Phase B: true logits, wave wv handles rows wv*4..wv*4+3
    #pragma unroll
    for (int j = 0; j < 4; ++j) {
        int r = wv * 4 + j;
        int b = b0 + r;
        int lab = labels[b];                       // wave-uniform
        float4 w4 = *(const float4*)(nce_weights + (size_t)lab * EMB + lane * 4);
        ushort4 e = *(const ushort4*)(A + r * LDA + lane * 4);
        float p = bf2f(e.x) * w4.x + bf2f(e.y) * w4.y +
                  bf2f(e.z) * w4.z + bf2f(e.w) * w4.w;
        #pragma unroll
        for (int o = 32; o > 0; o >>= 1) p += __shfl_down(p, o, 64);
        if (lane == 0) {
            float tl = p + nce_biases[lab] - log_corr(lab);
            myloss += fmaxf(tl, 0.0f) - tl + log1pf(expf(-fabsf(tl)));
        }
    }

    // Phase C: MFMA. Wave wv owns all 16 rows x samples wv*64..wv*64+63.
    const int l15 = lane & 15;
    const int lq  = lane >> 4;
    const unsigned short* Arow = A + l15 * LDA + lq * 8;
    const bf16x8* Bv = (const bf16x8*)Bsw;

    f32x4 acc[4];
    #pragma unroll
    for (int tt = 0; tt < 4; ++tt) acc[tt] = (f32x4){0.f, 0.f, 0.f, 0.f};

    #pragma unroll
    for (int kb = 0; kb < 8; ++kb) {
        bf16x8 af = *(const bf16x8*)(Arow + kb * 32);       // ds_read_b128
        #pragma unroll
        for (int tt = 0; tt < 4; ++tt) {
            int T = wv * 4 + tt;
            bf16x8 bfm = Bv[(T * 8 + kb) * 64 + lane];      // contiguous 1KB/wave, L2-hit
            acc[tt] = __builtin_amdgcn_mfma_f32_16x16x32_bf16(af, bfm, acc[tt], 0, 0, 0);
        }
    }

    // Epilogue: x = acc + sc[n]; xent label=0
    #pragma unroll
    for (int tt = 0; tt < 4; ++tt) {
        float scv = sc_l[wv * 64 + tt * 16 + l15];
        #pragma unroll
        for (int i = 0; i < 4; ++i) {
            float x = acc[tt][i] + scv;
            myloss += fmaxf(x, 0.0f) + log1pf(expf(-fabsf(x)));
        }
    }

    // block reduce + one atomic
    #pragma unroll
    for (int o = 32; o > 0; o >>= 1) myloss += __shfl_down(myloss, o, 64);
    if (lane == 0) wpart[wv] = myloss;
    __syncthreads();
    if (t == 0) {
        float s = wpart[0] + wpart[1] + wpart[2] + wpart[3];
        atomicAdd(out_cost, s * (1.0f / (float)BATCH_SZ));
    }
}

extern "C" void kernel_launch(void* const* d_in, const int* in_sizes, int n_in,
                              void* d_out, int out_size, void* d_ws, size_t ws_size,
                              hipStream_t stream) {
    const float* embeddings  = (const float*)d_in[0];
    const float* nce_weights = (const float*)d_in[1];
    const float* nce_biases  = (const float*)d_in[2];
    const int*   inputs      = (const int*)d_in[3];
    const int*   labels      = (const int*)d_in[4];
    const int*   sampled_ids = (const int*)d_in[5];

    float* out      = (float*)d_out;
    float* out_cost = out + (size_t)BATCH_SZ * EMB;

    unsigned short* Bsw  = (unsigned short*)d_ws;                      // 128 KB
    float*          scws = (float*)((char*)d_ws + NS * EMB * sizeof(unsigned short));

    nce_prep<<<NS * 32 / 64, 64, 0, stream>>>(
        nce_weights, nce_biases, sampled_ids, Bsw, scws, out_cost);

    nce_main<<<BATCH_SZ / ROWS, 256, 0, stream>>>(
        embeddings, nce_weights, nce_biases, inputs, labels,
        Bsw, scws, out, out_cost);
}

// Round 4
// 217.514 us; speedup vs baseline: 1.2564x; 1.0003x over previous
//
#include <hip/hip_runtime.h>
#include <math.h>

#define EMB 256
#define NS 256
#define BATCH_SZ 16384
#define ROWS 16            // batch rows per block
#define LDA 264            // padded LDS row stride (bf16 elems)

typedef __attribute__((ext_vector_type(8))) __bf16 bf16x8;
typedef __attribute__((ext_vector_type(4))) float  f32x4;

// log(NS * logUniformProb(id))
__device__ __forceinline__ float log_corr(int id) {
    const float INV_LOG_RANGE = 1.0f / 11.5129354649f;  // 1/ln(100001)
    float p = log1pf(1.0f / ((float)id + 1.0f)) * INV_LOG_RANGE;
    return logf((float)NS * p);
}
__device__ __forceinline__ unsigned short f2bf(float x) {
    unsigned int u = __float_as_uint(x);
    u += 0x7FFFu + ((u >> 16) & 1u);
    return (unsigned short)(u >> 16);
}

// ---- prep: gather sampled weight rows into MFMA-fragment-swizzled bf16 B ----
// Bsw element (T, kb, lane, j) = W[s = T*16 + (lane&15)][k = kb*32 + (lane>>4)*8 + j]
extern "C" __global__ void __launch_bounds__(64)
nce_prep(const float* __restrict__ nce_weights,
         const float* __restrict__ nce_biases,
         const int*   __restrict__ sampled_ids,
         unsigned short* __restrict__ Bsw,
         float* __restrict__ scws,
         float* __restrict__ out_cost)
{
    const int tid = blockIdx.x * 64 + threadIdx.x;   // 0..8191
    const int s   = tid >> 5;                        // sample 0..255
    const int u   = tid & 31;                        // 8-elem k-chunk 0..31
    const int sid = sampled_ids[s];
    const float4* wr = (const float4*)(nce_weights + (size_t)sid * EMB + u * 8);
    float4 a = wr[0], b = wr[1];
    unsigned short o[8] = { f2bf(a.x), f2bf(a.y), f2bf(a.z), f2bf(a.w),
                            f2bf(b.x), f2bf(b.y), f2bf(b.z), f2bf(b.w) };
    const int T = s >> 4, kb = u >> 2;
    const int lane = ((u & 3) << 4) | (s & 15);
    unsigned short* dst = Bsw + ((size_t)((T * 8 + kb) * 64 + lane)) * 8;
    *(ushort4*)(dst)     = *(ushort4*)&o[0];
    *(ushort4*)(dst + 4) = *(ushort4*)&o[4];
    if (u == 0) scws[s] = nce_biases[sid] - log_corr(sid);
    if (tid == 0) *out_cost = 0.0f;    // main kernel runs after on same stream
}

// ---- main: 2048 blocks x 256 thr; block = (16 batch rows) x (128 samples) ----
// split = blockIdx&1 selects sample half; split 0 also writes out_embed and
// computes true logits as the diagonal of an extra MFMA tile (wave 0).
extern "C" __global__ void __launch_bounds__(256, 8)
nce_main(const float* __restrict__ embeddings,
         const float* __restrict__ nce_weights,
         const float* __restrict__ nce_biases,
         const int*   __restrict__ inputs,
         const int*   __restrict__ labels,
         const unsigned short* __restrict__ Bsw,
         const float* __restrict__ scws,
         float* __restrict__ out_embed,
         float* __restrict__ out_cost)
{
    __shared__ unsigned short A[ROWS * LDA];   // 8.25 KB bf16 embed tile
    __shared__ float sc_l[NS];
    __shared__ float wpart[4];

    const int t     = threadIdx.x;
    const int lane  = t & 63;
    const int wv    = t >> 6;
    const int split = blockIdx.x & 1;
    const int b0    = (blockIdx.x >> 1) * ROWS;
    const int l15   = lane & 15;
    const int lq    = lane >> 4;
    const bool w0s0 = (wv == 0) && (split == 0);

    sc_l[t] = scws[t];

    // One coalesced 64B index load per wave; lane r holds inputs[b0+r].
    const int idxv = inputs[b0 + l15];
    int labv = 0;
    if (w0s0) labv = labels[b0 + l15];   // lane l15 -> its label row

    // Phase A: gather 16 embed rows (4 per wave, all loads independent)
    #pragma unroll
    for (int i = 0; i < 4; ++i) {
        int r = i * 4 + wv;
        int idx = __shfl(idxv, r, 64);
        const float4 v = *(const float4*)(embeddings + (size_t)idx * EMB + lane * 4);
        if (split == 0)
            *(float4*)(out_embed + (size_t)(b0 + r) * EMB + lane * 4) = v;
        ushort4 o;
        o.x = f2bf(v.x); o.y = f2bf(v.y); o.z = f2bf(v.z); o.w = f2bf(v.w);
        *(ushort4*)(A + r * LDA + lane * 4) = o;
    }
    __syncthreads();

    // Phase C: 2 sample tiles per wave (+1 true tile on wave 0 / split 0).
    const unsigned short* Arow = A + l15 * LDA + lq * 8;
    const bf16x8* Bv = (const bf16x8*)Bsw;
    const int T0 = split * 8 + wv * 2;           // first sample tile index

    f32x4 acc0 = (f32x4){0.f, 0.f, 0.f, 0.f};
    f32x4 acc1 = (f32x4){0.f, 0.f, 0.f, 0.f};
    f32x4 tacc = (f32x4){0.f, 0.f, 0.f, 0.f};

    const float* wtrue = nce_weights + (size_t)labv * EMB + lq * 8;

    #pragma unroll
    for (int kb = 0; kb < 8; ++kb) {
        bf16x8 af = *(const bf16x8*)(Arow + kb * 32);         // ds_read_b128
        bf16x8 bf0 = Bv[((T0 + 0) * 8 + kb) * 64 + lane];     // 1KB/wave, L2
        bf16x8 bf1 = Bv[((T0 + 1) * 8 + kb) * 64 + lane];
        acc0 = __builtin_amdgcn_mfma_f32_16x16x32_bf16(af, bf0, acc0, 0, 0, 0);
        acc1 = __builtin_amdgcn_mfma_f32_16x16x32_bf16(af, bf1, acc1, 0, 0, 0);
        if (w0s0) {
            const float4* wr = (const float4*)(wtrue + kb * 32);
            float4 a = wr[0], b = wr[1];
            unsigned short o[8] __attribute__((aligned(16))) =
                { f2bf(a.x), f2bf(a.y), f2bf(a.z), f2bf(a.w),
                  f2bf(b.x), f2bf(b.y), f2bf(b.z), f2bf(b.w) };
            bf16x8 tb = *(bf16x8*)o;
            tacc = __builtin_amdgcn_mfma_f32_16x16x32_bf16(af, tb, tacc, 0, 0, 0);
        }
    }

    float myloss = 0.0f;

    // sampled xent (label=0): x -> max(x,0)+log1p(exp(-|x|))
    {
        float sc0 = sc_l[(T0 + 0) * 16 + l15];
        float sc1 = sc_l[(T0 + 1) * 16 + l15];
        #pragma unroll
        for (int i = 0; i < 4; ++i) {
            float x0 = acc0[i] + sc0;
            float x1 = acc1[i] + sc1;
            myloss += fmaxf(x0, 0.0f) + log1pf(expf(-fabsf(x0)));
            myloss += fmaxf(x1, 0.0f) + log1pf(expf(-fabsf(x1)));
        }
    }

    // true xent (label=1) from the diagonal of tacc: C[row][col], col=l15,
    // row=lq*4+i; diagonal lives where lq == l15>>2 at i = l15&3.
    if (w0s0 && (lq == (l15 >> 2))) {
        float tl = tacc[l15 & 3] + nce_biases[labv] - log_corr(labv);
        myloss += fmaxf(tl, 0.0f) - tl + log1pf(expf(-fabsf(tl)));
    }

    // block reduce + one atomic
    #pragma unroll
    for (int o = 32; o > 0; o >>= 1) myloss += __shfl_down(myloss, o, 64);
    if (lane == 0) wpart[wv] = myloss;
    __syncthreads();
    if (t == 0) {
        float s = wpart[0] + wpart[1] + wpart[2] + wpart[3];
        atomicAdd(out_cost, s * (1.0f / (float)BATCH_SZ));
    }
}

extern "C" void kernel_launch(void* const* d_in, const int* in_sizes, int n_in,
                              void* d_out, int out_size, void* d_ws, size_t ws_size,
                              hipStream_t stream) {
    const float* embeddings  = (const float*)d_in[0];
    const float* nce_weights = (const float*)d_in[1];
    const float* nce_biases  = (const float*)d_in[2];
    const int*   inputs      = (const int*)d_in[3];
    const int*   labels      = (const int*)d_in[4];
    const int*   sampled_ids = (const int*)d_in[5];

    float* out      = (float*)d_out;
    float* out_cost = out + (size_t)BATCH_SZ * EMB;

    unsigned short* Bsw  = (unsigned short*)d_ws;                      // 128 KB
    float*          scws = (float*)((char*)d_ws + NS * EMB * sizeof(unsigned short));

    nce_prep<<<NS * 32 / 64, 64, 0, stream>>>(
        nce_weights, nce_biases, sampled_ids, Bsw, scws, out_cost);

    nce_main<<<(BATCH_SZ / ROWS) * 2, 256, 0, stream>>>(
        embeddings, nce_weights, nce_biases, inputs, labels,
        Bsw, scws, out, out_cost);
}

// Round 5
// 212.293 us; speedup vs baseline: 1.2873x; 1.0246x over previous
//
#include <hip/hip_runtime.h>
#include <math.h>

#define EMB 256
#define NS 256
#define BATCH_SZ 16384
#define ROWS 16            // batch rows per block
#define LDA 264            // padded LDS row stride (bf16 elems)
#define NBLK ((BATCH_SZ / ROWS) * 2)   // 2048 main blocks

typedef __attribute__((ext_vector_type(8))) __bf16 bf16x8;
typedef __attribute__((ext_vector_type(4))) float  f32x4;

// log(NS * logUniformProb(id))
__device__ __forceinline__ float log_corr(int id) {
    const float INV_LOG_RANGE = 1.0f / 11.5129354649f;  // 1/ln(100001)
    float p = log1pf(1.0f / ((float)id + 1.0f)) * INV_LOG_RANGE;
    return logf((float)NS * p);
}
__device__ __forceinline__ unsigned short f2bf(float x) {
    unsigned int u = __float_as_uint(x);
    u += 0x7FFFu + ((u >> 16) & 1u);
    return (unsigned short)(u >> 16);
}

// ---- prep: gather sampled weight rows into MFMA-fragment-swizzled bf16 B ----
// Bsw element (T, kb, lane, j) = W[s = T*16 + (lane&15)][k = kb*32 + (lane>>4)*8 + j]
extern "C" __global__ void __launch_bounds__(64)
nce_prep(const float* __restrict__ nce_weights,
         const float* __restrict__ nce_biases,
         const int*   __restrict__ sampled_ids,
         unsigned short* __restrict__ Bsw,
         float* __restrict__ scws)
{
    const int tid = blockIdx.x * 64 + threadIdx.x;   // 0..8191
    const int s   = tid >> 5;                        // sample 0..255
    const int u   = tid & 31;                        // 8-elem k-chunk 0..31
    const int sid = sampled_ids[s];
    const float4* wr = (const float4*)(nce_weights + (size_t)sid * EMB + u * 8);
    float4 a = wr[0], b = wr[1];
    unsigned short o[8] = { f2bf(a.x), f2bf(a.y), f2bf(a.z), f2bf(a.w),
                            f2bf(b.x), f2bf(b.y), f2bf(b.z), f2bf(b.w) };
    const int T = s >> 4, kb = u >> 2;
    const int lane = ((u & 3) << 4) | (s & 15);
    unsigned short* dst = Bsw + ((size_t)((T * 8 + kb) * 64 + lane)) * 8;
    *(ushort4*)(dst)     = *(ushort4*)&o[0];
    *(ushort4*)(dst + 4) = *(ushort4*)&o[4];
    if (u == 0) scws[s] = nce_biases[sid] - log_corr(sid);
}

// ---- main: 2048 blocks x 256 thr; block = (16 batch rows) x (128 samples) ----
// split = blockIdx&1 selects sample half; split 0 also writes out_embed and
// computes true logits as the diagonal of an extra MFMA tile (wave 0).
// Block partial loss -> plain store to partials[blockIdx] (NO atomic).
extern "C" __global__ void __launch_bounds__(256, 8)
nce_main(const float* __restrict__ embeddings,
         const float* __restrict__ nce_weights,
         const float* __restrict__ nce_biases,
         const int*   __restrict__ inputs,
         const int*   __restrict__ labels,
         const unsigned short* __restrict__ Bsw,
         const float* __restrict__ scws,
         float* __restrict__ out_embed,
         float* __restrict__ partials)
{
    __shared__ unsigned short A[ROWS * LDA];   // 8.25 KB bf16 embed tile
    __shared__ float sc_l[NS];
    __shared__ float wpart[4];

    const int t     = threadIdx.x;
    const int lane  = t & 63;
    const int wv    = t >> 6;
    const int split = blockIdx.x & 1;
    const int b0    = (blockIdx.x >> 1) * ROWS;
    const int l15   = lane & 15;
    const int lq    = lane >> 4;
    const bool w0s0 = (wv == 0) && (split == 0);

    sc_l[t] = scws[t];

    // One coalesced 64B index load per wave; lane r holds inputs[b0+r].
    const int idxv = inputs[b0 + l15];
    int labv = 0;
    if (w0s0) labv = labels[b0 + l15];   // lane l15 -> its label row

    // Phase A: gather 16 embed rows (4 per wave, all loads independent)
    #pragma unroll
    for (int i = 0; i < 4; ++i) {
        int r = i * 4 + wv;
        int idx = __shfl(idxv, r, 64);
        const float4 v = *(const float4*)(embeddings + (size_t)idx * EMB + lane * 4);
        if (split == 0)
            *(float4*)(out_embed + (size_t)(b0 + r) * EMB + lane * 4) = v;
        ushort4 o;
        o.x = f2bf(v.x); o.y = f2bf(v.y); o.z = f2bf(v.z); o.w = f2bf(v.w);
        *(ushort4*)(A + r * LDA + lane * 4) = o;
    }
    __syncthreads();

    // Phase C: 2 sample tiles per wave (+1 true tile on wave 0 / split 0).
    const unsigned short* Arow = A + l15 * LDA + lq * 8;
    const bf16x8* Bv = (const bf16x8*)Bsw;
    const int T0 = split * 8 + wv * 2;           // first sample tile index

    f32x4 acc0 = (f32x4){0.f, 0.f, 0.f, 0.f};
    f32x4 acc1 = (f32x4){0.f, 0.f, 0.f, 0.f};
    f32x4 tacc = (f32x4){0.f, 0.f, 0.f, 0.f};

    const float* wtrue = nce_weights + (size_t)labv * EMB + lq * 8;

    #pragma unroll
    for (int kb = 0; kb < 8; ++kb) {
        bf16x8 af = *(const bf16x8*)(Arow + kb * 32);         // ds_read_b128
        bf16x8 bf0 = Bv[((T0 + 0) * 8 + kb) * 64 + lane];     // 1KB/wave, L2
        bf16x8 bf1 = Bv[((T0 + 1) * 8 + kb) * 64 + lane];
        acc0 = __builtin_amdgcn_mfma_f32_16x16x32_bf16(af, bf0, acc0, 0, 0, 0);
        acc1 = __builtin_amdgcn_mfma_f32_16x16x32_bf16(af, bf1, acc1, 0, 0, 0);
        if (w0s0) {
            const float4* wr = (const float4*)(wtrue + kb * 32);
            float4 a = wr[0], b = wr[1];
            unsigned short o[8] __attribute__((aligned(16))) =
                { f2bf(a.x), f2bf(a.y), f2bf(a.z), f2bf(a.w),
                  f2bf(b.x), f2bf(b.y), f2bf(b.z), f2bf(b.w) };
            bf16x8 tb = *(bf16x8*)o;
            tacc = __builtin_amdgcn_mfma_f32_16x16x32_bf16(af, tb, tacc, 0, 0, 0);
        }
    }

    float myloss = 0.0f;

    // sampled xent (label=0): x -> max(x,0)+log1p(exp(-|x|))
    {
        float sc0 = sc_l[(T0 + 0) * 16 + l15];
        float sc1 = sc_l[(T0 + 1) * 16 + l15];
        #pragma unroll
        for (int i = 0; i < 4; ++i) {
            float x0 = acc0[i] + sc0;
            float x1 = acc1[i] + sc1;
            myloss += fmaxf(x0, 0.0f) + log1pf(expf(-fabsf(x0)));
            myloss += fmaxf(x1, 0.0f) + log1pf(expf(-fabsf(x1)));
        }
    }

    // true xent (label=1) from the diagonal of tacc: C[row][col], col=l15,
    // row=lq*4+i; diagonal lives where lq == l15>>2 at i = l15&3.
    if (w0s0 && (lq == (l15 >> 2))) {
        float tl = tacc[l15 & 3] + nce_biases[labv] - log_corr(labv);
        myloss += fmaxf(tl, 0.0f) - tl + log1pf(expf(-fabsf(tl)));
    }

    // block reduce + ONE plain store per block (no contended atomic)
    #pragma unroll
    for (int o = 32; o > 0; o >>= 1) myloss += __shfl_down(myloss, o, 64);
    if (lane == 0) wpart[wv] = myloss;
    __syncthreads();
    if (t == 0)
        partials[blockIdx.x] = wpart[0] + wpart[1] + wpart[2] + wpart[3];
}

// ---- final: reduce 2048 partials -> out_cost ----
extern "C" __global__ void __launch_bounds__(256)
nce_final(const float* __restrict__ partials, float* __restrict__ out_cost)
{
    __shared__ float wpart[4];
    const int t    = threadIdx.x;
    const int lane = t & 63;
    const int wv   = t >> 6;
    float s = 0.0f;
    #pragma unroll
    for (int i = 0; i < NBLK / 256; ++i) s += partials[i * 256 + t];
    #pragma unroll
    for (int o = 32; o > 0; o >>= 1) s += __shfl_down(s, o, 64);
    if (lane == 0) wpart[wv] = s;
    __syncthreads();
    if (t == 0)
        *out_cost = (wpart[0] + wpart[1] + wpart[2] + wpart[3]) * (1.0f / (float)BATCH_SZ);
}

extern "C" void kernel_launch(void* const* d_in, const int* in_sizes, int n_in,
                              void* d_out, int out_size, void* d_ws, size_t ws_size,
                              hipStream_t stream) {
    const float* embeddings  = (const float*)d_in[0];
    const float* nce_weights = (const float*)d_in[1];
    const float* nce_biases  = (const float*)d_in[2];
    const int*   inputs      = (const int*)d_in[3];
    const int*   labels      = (const int*)d_in[4];
    const int*   sampled_ids = (const int*)d_in[5];

    float* out      = (float*)d_out;
    float* out_cost = out + (size_t)BATCH_SZ * EMB;

    unsigned short* Bsw      = (unsigned short*)d_ws;                  // 128 KB
    float*          scws     = (float*)((char*)d_ws + NS * EMB * sizeof(unsigned short));
    float*          partials = scws + NS;                              // 8 KB

    nce_prep<<<NS * 32 / 64, 64, 0, stream>>>(
        nce_weights, nce_biases, sampled_ids, Bsw, scws);

    nce_main<<<NBLK, 256, 0, stream>>>(
        embeddings, nce_weights, nce_biases, inputs, labels,
        Bsw, scws, out, partials);

    nce_final<<<1, 256, 0, stream>>>(partials, out_cost);
}

// Round 6
// 204.692 us; speedup vs baseline: 1.3351x; 1.0371x over previous
//
#include <hip/hip_runtime.h>
#include <math.h>

#define EMB 256
#define NS 256
#define BATCH_SZ 16384
#define ROWS 16            // batch rows per block
#define LDA 264            // padded LDS row stride (bf16 elems)
#define NBLK (BATCH_SZ / ROWS)   // 1024 main blocks

typedef __attribute__((ext_vector_type(8))) __bf16 bf16x8;
typedef __attribute__((ext_vector_type(4))) float  f32x4;

// log(NS * logUniformProb(id))
__device__ __forceinline__ float log_corr(int id) {
    const float INV_LOG_RANGE = 1.0f / 11.5129354649f;  // 1/ln(100001)
    float p = log1pf(1.0f / ((float)id + 1.0f)) * INV_LOG_RANGE;
    return logf((float)NS * p);
}
__device__ __forceinline__ unsigned short f2bf(float x) {
    unsigned int u = __float_as_uint(x);
    u += 0x7FFFu + ((u >> 16) & 1u);
    return (unsigned short)(u >> 16);
}
__device__ __forceinline__ float bf2f(unsigned short b) {
    return __uint_as_float(((unsigned int)b) << 16);
}
// fast softplus(-|x|): log1p(exp(-a)), a>=0. HW exp/log; err < 1e-7 absolute.
__device__ __forceinline__ float softplus_neg(float a) {
    return __logf(1.0f + __expf(-a));
}

// ---- prep: gather sampled weight rows into MFMA-fragment-swizzled bf16 B ----
// Bsw element (T, kb, lane, j) = W[s = T*16 + (lane&15)][k = kb*32 + (lane>>4)*8 + j]
extern "C" __global__ void __launch_bounds__(64)
nce_prep(const float* __restrict__ nce_weights,
         const float* __restrict__ nce_biases,
         const int*   __restrict__ sampled_ids,
         unsigned short* __restrict__ Bsw,
         float* __restrict__ scws)
{
    const int tid = blockIdx.x * 64 + threadIdx.x;   // 0..8191
    const int s   = tid >> 5;                        // sample 0..255
    const int u   = tid & 31;                        // 8-elem k-chunk 0..31
    const int sid = sampled_ids[s];
    const float4* wr = (const float4*)(nce_weights + (size_t)sid * EMB + u * 8);
    float4 a = wr[0], b = wr[1];
    unsigned short o[8] = { f2bf(a.x), f2bf(a.y), f2bf(a.z), f2bf(a.w),
                            f2bf(b.x), f2bf(b.y), f2bf(b.z), f2bf(b.w) };
    const int T = s >> 4, kb = u >> 2;
    const int lane = ((u & 3) << 4) | (s & 15);
    unsigned short* dst = Bsw + ((size_t)((T * 8 + kb) * 64 + lane)) * 8;
    *(ushort4*)(dst)     = *(ushort4*)&o[0];
    *(ushort4*)(dst + 4) = *(ushort4*)&o[4];
    if (u == 0) scws[s] = nce_biases[sid] - log_corr(sid);
}

// ---- main: 1024 blocks x 256 thr; block = 16 batch rows x all 256 samples ----
extern "C" __global__ void __launch_bounds__(256, 4)
nce_main(const float* __restrict__ embeddings,
         const float* __restrict__ nce_weights,
         const float* __restrict__ nce_biases,
         const int*   __restrict__ inputs,
         const int*   __restrict__ labels,
         const unsigned short* __restrict__ Bsw,
         const float* __restrict__ scws,
         float* __restrict__ out_embed,
         float* __restrict__ partials)
{
    __shared__ unsigned short A[ROWS * LDA];   // 8.25 KB bf16 embed tile
    __shared__ float sc_l[NS];
    __shared__ float wpart[4];

    const int t    = threadIdx.x;
    const int lane = t & 63;
    const int wv   = t >> 6;
    const int b0   = blockIdx.x * ROWS;
    const int l15  = lane & 15;
    const int lq   = lane >> 4;

    sc_l[t] = scws[t];

    // One coalesced 64B index/label load per wave; lane r holds row b0+r's value.
    const int idxv = inputs[b0 + l15];
    const int labv = labels[b0 + l15];

    // Phase A: gather 16 embed rows (4 per wave, loads independent)
    #pragma unroll
    for (int i = 0; i < 4; ++i) {
        int r = i * 4 + wv;
        int idx = __shfl(idxv, r, 64);
        const float4 v = *(const float4*)(embeddings + (size_t)idx * EMB + lane * 4);
        *(float4*)(out_embed + (size_t)(b0 + r) * EMB + lane * 4) = v;
        ushort4 o;
        o.x = f2bf(v.x); o.y = f2bf(v.y); o.z = f2bf(v.z); o.w = f2bf(v.w);
        *(ushort4*)(A + r * LDA + lane * 4) = o;
    }
    __syncthreads();

    float myloss = 0.0f;

    // Phase B: true logits; wave wv handles rows wv*4..wv*4+3
    #pragma unroll
    for (int j = 0; j < 4; ++j) {
        int r = wv * 4 + j;
        int lab = __shfl(labv, r, 64);             // wave-uniform
        float4 w4 = *(const float4*)(nce_weights + (size_t)lab * EMB + lane * 4);
        ushort4 e = *(const ushort4*)(A + r * LDA + lane * 4);
        float p = bf2f(e.x) * w4.x + bf2f(e.y) * w4.y +
                  bf2f(e.z) * w4.z + bf2f(e.w) * w4.w;
        #pragma unroll
        for (int o = 32; o > 0; o >>= 1) p += __shfl_down(p, o, 64);
        if (lane == 0) {
            float tl = p + nce_biases[lab] - log_corr(lab);
            myloss += fmaxf(tl, 0.0f) - tl + softplus_neg(fabsf(tl));
        }
    }

    // Phase C: MFMA; wave wv owns all 16 rows x samples wv*64..wv*64+63.
    const unsigned short* Arow = A + l15 * LDA + lq * 8;
    const bf16x8* Bv = (const bf16x8*)Bsw;

    f32x4 acc[4];
    #pragma unroll
    for (int tt = 0; tt < 4; ++tt) acc[tt] = (f32x4){0.f, 0.f, 0.f, 0.f};

    #pragma unroll
    for (int kb = 0; kb < 8; ++kb) {
        bf16x8 af = *(const bf16x8*)(Arow + kb * 32);       // ds_read_b128
        #pragma unroll
        for (int tt = 0; tt < 4; ++tt) {
            int T = wv * 4 + tt;
            bf16x8 bfm = Bv[(T * 8 + kb) * 64 + lane];      // 1KB/wave, L2-hit
            acc[tt] = __builtin_amdgcn_mfma_f32_16x16x32_bf16(af, bfm, acc[tt], 0, 0, 0);
        }
    }

    // Epilogue: x = acc + sc[n]; xent label=0
    #pragma unroll
    for (int tt = 0; tt < 4; ++tt) {
        float scv = sc_l[wv * 64 + tt * 16 + l15];
        #pragma unroll
        for (int i = 0; i < 4; ++i) {
            float x = acc[tt][i] + scv;
            myloss += fmaxf(x, 0.0f) + softplus_neg(fabsf(x));
        }
    }

    // block reduce + ONE plain store per block
    #pragma unroll
    for (int o = 32; o > 0; o >>= 1) myloss += __shfl_down(myloss, o, 64);
    if (lane == 0) wpart[wv] = myloss;
    __syncthreads();
    if (t == 0)
        partials[blockIdx.x] = wpart[0] + wpart[1] + wpart[2] + wpart[3];
}

// ---- final: reduce 1024 partials -> out_cost ----
extern "C" __global__ void __launch_bounds__(256)
nce_final(const float* __restrict__ partials, float* __restrict__ out_cost)
{
    __shared__ float wpart[4];
    const int t    = threadIdx.x;
    const int lane = t & 63;
    const int wv   = t >> 6;
    float s = 0.0f;
    #pragma unroll
    for (int i = 0; i < NBLK / 256; ++i) s += partials[i * 256 + t];
    #pragma unroll
    for (int o = 32; o > 0; o >>= 1) s += __shfl_down(s, o, 64);
    if (lane == 0) wpart[wv] = s;
    __syncthreads();
    if (t == 0)
        *out_cost = (wpart[0] + wpart[1] + wpart[2] + wpart[3]) * (1.0f / (float)BATCH_SZ);
}

extern "C" void kernel_launch(void* const* d_in, const int* in_sizes, int n_in,
                              void* d_out, int out_size, void* d_ws, size_t ws_size,
                              hipStream_t stream) {
    const float* embeddings  = (const float*)d_in[0];
    const float* nce_weights = (const float*)d_in[1];
    const float* nce_biases  = (const float*)d_in[2];
    const int*   inputs      = (const int*)d_in[3];
    const int*   labels      = (const int*)d_in[4];
    const int*   sampled_ids = (const int*)d_in[5];

    float* out      = (float*)d_out;
    float* out_cost = out + (size_t)BATCH_SZ * EMB;

    unsigned short* Bsw      = (unsigned short*)d_ws;                  // 128 KB
    float*          scws     = (float*)((char*)d_ws + NS * EMB * sizeof(unsigned short));
    float*          partials = scws + NS;                              // 4 KB

    nce_prep<<<NS * 32 / 64, 64, 0, stream>>>(
        nce_weights, nce_biases, sampled_ids, Bsw, scws);

    nce_main<<<NBLK, 256, 0, stream>>>(
        embeddings, nce_weights, nce_biases, inputs, labels,
        Bsw, scws, out, partials);

    nce_final<<<1, 256, 0, stream>>>(partials, out_cost);
}